// Round 17
// baseline (131.459 us; speedup 1.0000x reference)
//
#include <hip/hip_runtime.h>

#define D_DIM 8192
#define SPLITK 4
#define KS 2048               // K per slice
#define BK 256                // floats per chunk (1-KB contiguous run per row)
#define NITER 8               // KS/BK
#define NGROUP 320            // 32-row groups (q:0-255, k:256-287, v:288-319)

#define PART_BYTES (SPLITK * NGROUP * 1024 * 4)   // 5,242,880

typedef float f32x4 __attribute__((ext_vector_type(4)));
typedef short s16x8 __attribute__((ext_vector_type(8)));
typedef short s16x4 __attribute__((ext_vector_type(4)));

static __device__ __forceinline__ unsigned short f2bf(float f) {
  union { float f; unsigned u; } v; v.f = f;
  return (unsigned short)((v.u + 0x7FFFu + ((v.u >> 16) & 1u)) >> 16);
}

static __device__ __forceinline__ s16x8 pack_bf16(f32x4 lo, f32x4 hi) {
  s16x8 r;
  r[0] = (short)f2bf(lo[0]); r[1] = (short)f2bf(lo[1]);
  r[2] = (short)f2bf(lo[2]); r[3] = (short)f2bf(lo[3]);
  r[4] = (short)f2bf(hi[0]); r[5] = (short)f2bf(hi[1]);
  r[6] = (short)f2bf(hi[2]); r[7] = (short)f2bf(hi[3]);
  return r;
}

// W stage: instruction J loads row (w*8+J)'s 1-KB chunk run; lane at col lane*4.
// NON-TEMPORAL (R16 win): weights are single-use — stream past L3.
#define WLOAD1(J, KO) \
    wreg##J = __builtin_nontemporal_load( \
        (const f32x4*)(wrow0 + (size_t)(w * 8 + J) * D_DIM + (KO) + lane * 4))

#define WLOAD(CH) do {                                                          \
    const size_t ko_ = kbase + (size_t)(CH) * BK;                               \
    WLOAD1(0, ko_); WLOAD1(1, ko_); WLOAD1(2, ko_); WLOAD1(3, ko_);             \
    WLOAD1(4, ko_); WLOAD1(5, ko_); WLOAD1(6, ko_); WLOAD1(7, ko_);             \
  } while (0)

// cvt fp32->bf16 and write 8B to XOR-swizzled LDS (16-B slot granularity).
// row rw: slot = (lane>>1) ^ ((rw&7)<<2), half = lane&1.
#define CVT1(J, BUF) do {                                                       \
    const int rw_ = w * 8 + J;                                                  \
    const int sl_ = ((lane >> 1) ^ ((rw_ & 7) << 2));                           \
    s16x4 v_;                                                                   \
    v_[0] = (short)f2bf(wreg##J[0]); v_[1] = (short)f2bf(wreg##J[1]);           \
    v_[2] = (short)f2bf(wreg##J[2]); v_[3] = (short)f2bf(wreg##J[3]);           \
    *(s16x4*)&ldsW[BUF][rw_ * BK + sl_ * 8 + (lane & 1) * 4] = v_;              \
  } while (0)

#define CVT_WRITE(BUF) do {                                                     \
    CVT1(0,BUF); CVT1(1,BUF); CVT1(2,BUF); CVT1(3,BUF);                         \
    CVT1(4,BUF); CVT1(5,BUF); CVT1(6,BUF); CVT1(7,BUF); } while (0)

// A-fragments for chunk C, loaded DIRECTLY from x (L2-hot) and cvt'd
// in-register — replaces the xprep kernel (same f2bf -> bitwise-identical).
// Fragment t: x[arow][kbase + C*BK + t*32 + kq*8 .. +8].
#define XF1(T, XB) do {                                                         \
    f32x4 lo_ = *(const f32x4*)((XB) + (T) * 32);                               \
    f32x4 hi_ = *(const f32x4*)((XB) + (T) * 32 + 4);                           \
    xq##T = pack_bf16(lo_, hi_);                                                \
  } while (0)

#define XLOADCVT(C) do {                                                        \
    const float* xb_ = xrow + kbase + (size_t)(C) * BK;                         \
    XF1(0, xb_); XF1(1, xb_); XF1(2, xb_); XF1(3, xb_);                         \
    XF1(4, xb_); XF1(5, xb_); XF1(6, xb_); XF1(7, xb_);                         \
  } while (0)

// One k-step: A from named reg, B from swizzled bf16 LDS. Regs+LDS only.
#define MFMA1(BUF, S) do {                                                      \
    const int sl_ = (((S) * 4 + kq) ^ ((brow & 7) << 2));                       \
    s16x8 fb_ = *(const s16x8*)&ldsW[BUF][brow * BK + sl_ * 8];                 \
    acc = __builtin_amdgcn_mfma_f32_16x16x32_bf16(xq##S, fb_, acc, 0, 0, 0);    \
  } while (0)

#define COMPUTE(BUF) do {                                                       \
    MFMA1(BUF,0); MFMA1(BUF,1); MFMA1(BUF,2); MFMA1(BUF,3);                     \
    MFMA1(BUF,4); MFMA1(BUF,5); MFMA1(BUF,6); MFMA1(BUF,7); } while (0)

__global__ __launch_bounds__(256, 4) void qkv_gemm(
    const float* __restrict__ x,  const float* __restrict__ wq,
    const float* __restrict__ wk, const float* __restrict__ wv,
    float* __restrict__ wsb)
{
  // W-only double buffer, bf16: 2 * 32*256 * 2B = 32 KiB
  __shared__ unsigned short ldsW[2][32 * BK];

  const int bid   = blockIdx.x;
  const int ksl   = bid & (SPLITK - 1);
  const int group = bid >> 2;                 // 0..319
  const int n0    = group * 32;

  const float* wptr; int erow0;
  if (n0 < 8192)      { wptr = wq; erow0 = n0; }
  else if (n0 < 9216) { wptr = wk; erow0 = n0 - 8192; }
  else                { wptr = wv; erow0 = n0 - 9216; }

  const int tid  = threadIdx.x;
  const int lane = tid & 63;
  const int w    = tid >> 6;
  const size_t kbase = (size_t)ksl * KS;

  const float* wrow0 = wptr + (size_t)erow0 * D_DIM;

  // MFMA fragment addressing
  const int wm   = w >> 1, wn = w & 1;
  const int la   = lane & 15;
  const int kq   = lane >> 4;
  const int brow = wn * 16 + la;
  const int arow = wm * 16 + la;

  // per-lane x base: row arow, k-offset kq*8 (verified fragment layout R9-R16)
  const float* xrow = x + (size_t)arow * D_DIM + kq * 8;

  f32x4 acc = {0.f, 0.f, 0.f, 0.f};
  f32x4 wreg0, wreg1, wreg2, wreg3, wreg4, wreg5, wreg6, wreg7;
  s16x8 xq0, xq1, xq2, xq3, xq4, xq5, xq6, xq7;

  WLOAD(0);

  // R13/R16 two-barrier dbuf loop; A-path now xprep-free.
  #pragma unroll
  for (int c = 0; c < NITER; ++c) {
    XLOADCVT(c);                      // L2-hit x loads + cvt (pre-barrier)
    CVT_WRITE(c & 1);                 // waits W(c) regs only
    if (c + 1 < NITER) WLOAD(c + 1);  // in flight across barrier + compute
    __syncthreads();                  // buf[c&1] visible to all waves
    COMPUTE(c & 1);                   // regs + LDS only
    __syncthreads();                  // all done reading buf[c&1]
  }

  // partial: ws[ksl][group][b*32+n]  (C/D: col=lane&15=n, row=kq*4+r=batch)
  const int m0 = kq * 4;
  float* p = wsb + ((size_t)(ksl * NGROUP + group)) * 1024;
  #pragma unroll
  for (int r = 0; r < 4; ++r)
    p[(wm * 16 + m0 + r) * 32 + wn * 16 + la] = acc[r];
}

// Sum SPLITK partial tiles per group and scatter to head-layout output.
__global__ __launch_bounds__(256) void qkv_reduce(
    const float* __restrict__ ws, float* __restrict__ out)
{
  const int group = blockIdx.x;
  const int idx   = threadIdx.x * 4;          // b*32 + n, 4 consecutive n
  f32x4 s = {0.f, 0.f, 0.f, 0.f};
  #pragma unroll
  for (int sl = 0; sl < SPLITK; ++sl) {
    f32x4 v = *(const f32x4*)(
        ws + ((size_t)(sl * NGROUP + group)) * 1024 + idx);
    s[0] += v[0]; s[1] += v[1]; s[2] += v[2]; s[3] += v[3];
  }
  const int b = idx >> 5;
  const int n = idx & 31;
  const int e = group * 32 + n;
  int outbase, er;
  if (e < 8192)      { outbase = 0;      er = e; }
  else if (e < 9216) { outbase = 262144; er = e - 8192; }
  else               { outbase = 294912; er = e - 9216; }
  *(f32x4*)(out + outbase + (er >> 7) * 4096 + b * 128 + (er & 127)) = s;
}

extern "C" void kernel_launch(void* const* d_in, const int* in_sizes, int n_in,
                              void* d_out, int out_size, void* d_ws, size_t ws_size,
                              hipStream_t stream) {
  const float* x  = (const float*)d_in[0];
  const float* wq = (const float*)d_in[1];
  const float* wk = (const float*)d_in[2];
  const float* wv = (const float*)d_in[3];
  float* out = (float*)d_out;

  float* part = (float*)d_ws;

  qkv_gemm<<<dim3(NGROUP * SPLITK), dim3(256), 0, stream>>>(
      x, wq, wk, wv, part);
  qkv_reduce<<<dim3(NGROUP), dim3(256), 0, stream>>>((const float*)part, out);
}

// Round 18
// 83.056 us; speedup vs baseline: 1.5828x; 1.5828x over previous
//
#include <hip/hip_runtime.h>

#define D_DIM 8192
#define SPLITK 4
#define KS 2048               // K per slice
#define BK 256                // floats per chunk (1-KB contiguous run per row)
#define NITER 8               // KS/BK
#define NGROUP 320            // 32-row groups (q:0-255, k:256-287, v:288-319)

#define PART_BYTES (SPLITK * NGROUP * 1024 * 4)   // 5,242,880
#define XF_BYTES   (256 * 2 * 64 * 8 * 2)         // 524,288

typedef float f32x4 __attribute__((ext_vector_type(4)));
typedef short s16x8 __attribute__((ext_vector_type(8)));
typedef short s16x4 __attribute__((ext_vector_type(4)));

static __device__ __forceinline__ unsigned short f2bf(float f) {
  union { float f; unsigned u; } v; v.f = f;
  return (unsigned short)((v.u + 0x7FFFu + ((v.u >> 16) & 1u)) >> 16);
}

// Precompute X fragments in per-lane MFMA A-operand order:
// xf[kstep][wm][lane][8] bf16, kstep = 0..255 over full D. (verified R9-R16)
// One coalesced reshape pass — R17 proved in-loop gather is 46 µs worse.
__global__ __launch_bounds__(256) void xprep(const float* __restrict__ x,
                                             unsigned short* __restrict__ xf) {
  const int cell = blockIdx.x * 256 + threadIdx.x;   // 32768 cells
  const int lane = cell & 63;
  const int wm   = (cell >> 6) & 1;
  const int kst  = cell >> 7;
  const float* s = x + (size_t)(wm * 16 + (lane & 15)) * D_DIM
                     + kst * 32 + (lane >> 4) * 8;
  f32x4 lo = *(const f32x4*)s;
  f32x4 hi = *(const f32x4*)(s + 4);
  s16x8 v;
  v[0]=(short)f2bf(lo[0]); v[1]=(short)f2bf(lo[1]);
  v[2]=(short)f2bf(lo[2]); v[3]=(short)f2bf(lo[3]);
  v[4]=(short)f2bf(hi[0]); v[5]=(short)f2bf(hi[1]);
  v[6]=(short)f2bf(hi[2]); v[7]=(short)f2bf(hi[3]);
  *(s16x8*)&xf[(size_t)cell * 8] = v;
}

// W stage: instruction J loads row (w*8+J)'s 1-KB chunk run; lane at col lane*4.
// NON-TEMPORAL (R16 win, +2.8%): weights are single-use — stream past L3.
#define WLOAD1(J, KO) \
    wreg##J = __builtin_nontemporal_load( \
        (const f32x4*)(wrow0 + (size_t)(w * 8 + J) * D_DIM + (KO) + lane * 4))

#define WLOAD(CH) do {                                                          \
    const size_t ko_ = kbase + (size_t)(CH) * BK;                               \
    WLOAD1(0, ko_); WLOAD1(1, ko_); WLOAD1(2, ko_); WLOAD1(3, ko_);             \
    WLOAD1(4, ko_); WLOAD1(5, ko_); WLOAD1(6, ko_); WLOAD1(7, ko_);             \
  } while (0)

// cvt fp32->bf16 and write 8B to XOR-swizzled LDS (16-B slot granularity).
// row rw: slot = (lane>>1) ^ ((rw&7)<<2), half = lane&1.
#define CVT1(J, BUF) do {                                                       \
    const int rw_ = w * 8 + J;                                                  \
    const int sl_ = ((lane >> 1) ^ ((rw_ & 7) << 2));                           \
    s16x4 v_;                                                                   \
    v_[0] = (short)f2bf(wreg##J[0]); v_[1] = (short)f2bf(wreg##J[1]);           \
    v_[2] = (short)f2bf(wreg##J[2]); v_[3] = (short)f2bf(wreg##J[3]);           \
    *(s16x4*)&ldsW[BUF][rw_ * BK + sl_ * 8 + (lane & 1) * 4] = v_;              \
  } while (0)

#define CVT_WRITE(BUF) do {                                                     \
    CVT1(0,BUF); CVT1(1,BUF); CVT1(2,BUF); CVT1(3,BUF);                         \
    CVT1(4,BUF); CVT1(5,BUF); CVT1(6,BUF); CVT1(7,BUF); } while (0)

// Prefetch the 8 A-fragments of chunk C into NAMED regs (L2-hot, 16B each).
#define XFLOAD(C) do {                                                          \
    const unsigned short* xb_ = xfp + (size_t)((C) * 16 + wm) * 512 + lane * 8; \
    xq0 = *(const s16x8*)(xb_);          xq1 = *(const s16x8*)(xb_ + 1024);     \
    xq2 = *(const s16x8*)(xb_ + 2048);   xq3 = *(const s16x8*)(xb_ + 3072);     \
    xq4 = *(const s16x8*)(xb_ + 4096);   xq5 = *(const s16x8*)(xb_ + 5120);     \
    xq6 = *(const s16x8*)(xb_ + 6144);   xq7 = *(const s16x8*)(xb_ + 7168);     \
  } while (0)

// One k-step: A from named reg, B from swizzled bf16 LDS. Regs+LDS only.
#define MFMA1(BUF, S) do {                                                      \
    const int sl_ = (((S) * 4 + kq) ^ ((brow & 7) << 2));                       \
    s16x8 fb_ = *(const s16x8*)&ldsW[BUF][brow * BK + sl_ * 8];                 \
    acc = __builtin_amdgcn_mfma_f32_16x16x32_bf16(xq##S, fb_, acc, 0, 0, 0);    \
  } while (0)

#define COMPUTE(BUF) do {                                                       \
    MFMA1(BUF,0); MFMA1(BUF,1); MFMA1(BUF,2); MFMA1(BUF,3);                     \
    MFMA1(BUF,4); MFMA1(BUF,5); MFMA1(BUF,6); MFMA1(BUF,7); } while (0)

__global__ __launch_bounds__(256, 4) void qkv_gemm(
    const float* __restrict__ wq, const float* __restrict__ wk,
    const float* __restrict__ wv, const unsigned short* __restrict__ xf,
    float* __restrict__ wsb)
{
  // W-only double buffer, bf16: 2 * 32*256 * 2B = 32 KiB
  __shared__ unsigned short ldsW[2][32 * BK];

  const int bid   = blockIdx.x;
  const int ksl   = bid & (SPLITK - 1);
  const int group = bid >> 2;                 // 0..319
  const int n0    = group * 32;

  const float* wptr; int erow0;
  if (n0 < 8192)      { wptr = wq; erow0 = n0; }
  else if (n0 < 9216) { wptr = wk; erow0 = n0 - 8192; }
  else                { wptr = wv; erow0 = n0 - 9216; }

  const int tid  = threadIdx.x;
  const int lane = tid & 63;
  const int w    = tid >> 6;
  const size_t kbase = (size_t)ksl * KS;

  // xf base for THIS k-slice (64 k-steps per slice; chunk c covers 8)
  const unsigned short* xfp = xf + (size_t)(ksl * 64 * 2) * 512;

  const float* wrow0 = wptr + (size_t)erow0 * D_DIM;

  // MFMA fragment addressing
  const int wm   = w >> 1, wn = w & 1;
  const int la   = lane & 15;
  const int kq   = lane >> 4;
  const int brow = wn * 16 + la;

  f32x4 acc = {0.f, 0.f, 0.f, 0.f};
  f32x4 wreg0, wreg1, wreg2, wreg3, wreg4, wreg5, wreg6, wreg7;
  s16x8 xq0, xq1, xq2, xq3, xq4, xq5, xq6, xq7;

  WLOAD(0);

  // R13 two-barrier dbuf loop (best measured config), nt W-loads.
  #pragma unroll
  for (int c = 0; c < NITER; ++c) {
    XFLOAD(c);                        // xq(c) issued before W(c+1): FIFO-safe
    CVT_WRITE(c & 1);                 // waits W(c) only
    if (c + 1 < NITER) WLOAD(c + 1);  // in flight across barrier + compute
    __syncthreads();                  // buf[c&1] visible to all waves
    COMPUTE(c & 1);                   // waits xq(c)
    __syncthreads();                  // all done reading buf[c&1]
  }

  // partial: ws[ksl][group][b*32+n]  (C/D: col=lane&15=n, row=kq*4+r=batch)
  const int m0 = kq * 4;
  float* p = wsb + ((size_t)(ksl * NGROUP + group)) * 1024;
  #pragma unroll
  for (int r = 0; r < 4; ++r)
    p[(wm * 16 + m0 + r) * 32 + wn * 16 + la] = acc[r];
}

// Sum SPLITK partial tiles per group and scatter to head-layout output.
__global__ __launch_bounds__(256) void qkv_reduce(
    const float* __restrict__ ws, float* __restrict__ out)
{
  const int group = blockIdx.x;
  const int idx   = threadIdx.x * 4;          // b*32 + n, 4 consecutive n
  f32x4 s = {0.f, 0.f, 0.f, 0.f};
  #pragma unroll
  for (int sl = 0; sl < SPLITK; ++sl) {
    f32x4 v = *(const f32x4*)(
        ws + ((size_t)(sl * NGROUP + group)) * 1024 + idx);
    s[0] += v[0]; s[1] += v[1]; s[2] += v[2]; s[3] += v[3];
  }
  const int b = idx >> 5;
  const int n = idx & 31;
  const int e = group * 32 + n;
  int outbase, er;
  if (e < 8192)      { outbase = 0;      er = e; }
  else if (e < 9216) { outbase = 262144; er = e - 8192; }
  else               { outbase = 294912; er = e - 9216; }
  *(f32x4*)(out + outbase + (er >> 7) * 4096 + b * 128 + (er & 127)) = s;
}

extern "C" void kernel_launch(void* const* d_in, const int* in_sizes, int n_in,
                              void* d_out, int out_size, void* d_ws, size_t ws_size,
                              hipStream_t stream) {
  const float* x  = (const float*)d_in[0];
  const float* wq = (const float*)d_in[1];
  const float* wk = (const float*)d_in[2];
  const float* wv = (const float*)d_in[3];
  float* out = (float*)d_out;

  float*          part = (float*)d_ws;
  unsigned short* xf   = (unsigned short*)((char*)d_ws + PART_BYTES);

  xprep<<<dim3(128), dim3(256), 0, stream>>>(x, xf);
  qkv_gemm<<<dim3(NGROUP * SPLITK), dim3(256), 0, stream>>>(
      wq, wk, wv, xf, part);
  qkv_reduce<<<dim3(NGROUP), dim3(256), 0, stream>>>((const float*)part, out);
}